// Round 5
// baseline (139.795 us; speedup 1.0000x reference)
//
#include <hip/hip_runtime.h>
#include <hip/hip_bf16.h>
#include <math.h>

#define D      256
#define N2     8192
#define NHALF  4096

typedef __bf16 bf16x8_t __attribute__((ext_vector_type(8)));
typedef __bf16 bf16x4_t __attribute__((ext_vector_type(4)));
typedef float  f32x4_t  __attribute__((ext_vector_type(4)));

// exp(2s) = 2^(2*log2e*s); prescale both GEMM operands by sqrt(2*log2e) so the
// MFMA accumulator is directly the exp2 argument.
#define SCL 1.6986437f   // sqrt(2 * 1.44269504)

// ---------------- kernel 1: fused normalize(+prescale) + positives + denom-zero ----
__global__ __launch_bounds__(256) void prep_kernel(const float* __restrict__ a,
                                                   const float* __restrict__ b,
                                                   __bf16* __restrict__ zb,
                                                   float* __restrict__ g_pos,
                                                   float* __restrict__ g_denom) {
    const int tid = threadIdx.x;
    const int gt  = blockIdx.x * 256 + tid;
    if (gt < N2) g_denom[gt] = 0.0f;

    const int w = blockIdx.x * 4 + (tid >> 6);  // pair row in [0, NHALF)
    const int l = tid & 63;
    float4 x = ((const float4*)(a + (size_t)w * D))[l];
    float4 y = ((const float4*)(b + (size_t)w * D))[l];
    float sxx = x.x * x.x + x.y * x.y + x.z * x.z + x.w * x.w;
    float syy = y.x * y.x + y.y * y.y + y.z * y.z + y.w * y.w;
    float sxy = x.x * y.x + x.y * y.y + x.z * y.z + x.w * y.w;
    #pragma unroll
    for (int off = 32; off; off >>= 1) {
        sxx += __shfl_xor(sxx, off, 64);
        syy += __shfl_xor(syy, off, 64);
        sxy += __shfl_xor(sxy, off, 64);
    }
    const float rx = 1.0f / fmaxf(sqrtf(sxx), 1e-8f);
    const float ry = 1.0f / fmaxf(sqrtf(syy), 1e-8f);
    const float sx = rx * SCL;
    const float sy = ry * SCL;

    bf16x4_t ox, oy;
    ox[0] = (__bf16)(x.x * sx); ox[1] = (__bf16)(x.y * sx);
    ox[2] = (__bf16)(x.z * sx); ox[3] = (__bf16)(x.w * sx);
    oy[0] = (__bf16)(y.x * sy); oy[1] = (__bf16)(y.y * sy);
    oy[2] = (__bf16)(y.z * sy); oy[3] = (__bf16)(y.w * sy);
    *(bf16x4_t*)(zb + (size_t)w * D + l * 4)           = ox;
    *(bf16x4_t*)(zb + (size_t)(w + NHALF) * D + l * 4) = oy;

    if (l == 0) {
        const float p = sxy * rx * ry;   // exact fp32 positive similarity
        g_pos[w]         = p;
        g_pos[w + NHALF] = p;
    }
}

// ---------------- kernel 2: one-wave blocks, reg-resident A, 32-col B strips -------
// Work item = one 64-thread block = one wave = (64-row band, chunk of <=8 strips of
// 32 cols covering the band's lower-triangle range). 2112 blocks. No LDS/barriers.
// __launch_bounds__(64,1) -> 512-VGPR budget so af[4][8] (128 VGPRs) is truly
// register-resident (R3/R4 allocator rematerialized A loads per strip at 92/124
// VGPRs). B strips double-buffered in registers; depth 1 hides L2 latency under
// the 64-MFMA strip body.
__global__ __launch_bounds__(64, 1) void sim_kernel(const __bf16* __restrict__ zb,
                                                    float* __restrict__ g_denom) {
    const int l      = threadIdx.x & 63;
    const int lane15 = l & 15;
    const int quad   = l >> 4;

    // decode block id -> (band, chunk): bands grouped by 4, group g has g+1 chunks
    // per band, cumulative 2g(g+1); 2112 total.
    const int wid = blockIdx.x;
    int g = (int)((sqrtf(2.0f * (float)wid + 1.0f) - 1.0f) * 0.5f);
    while (2 * (g + 1) * (g + 2) <= wid) ++g;
    while (2 * g * (g + 1) > wid) --g;
    const int rem   = wid - 2 * g * (g + 1);
    const int gp1   = g + 1;
    const int boff  = (rem >= gp1) + (rem >= 2 * gp1) + (rem >= 3 * gp1);
    const int band  = 4 * g + boff;
    const int chunk = rem - boff * gp1;
    const int r0    = band * 64;
    const int s0    = chunk * 8;                       // 32-col strips
    const int s1    = min(s0 + 8, 2 * band + 2);
    const int smask = 2 * band;                        // strips >= smask: col<row mask

    // A fragments: 64 rows x K=256, resident for the whole chunk (128 VGPRs)
    bf16x8_t af[4][8];
    {
        const __bf16* abase = zb + (size_t)(r0 + lane15) * D + quad * 8;
        #pragma unroll
        for (int mi = 0; mi < 4; ++mi)
            #pragma unroll
            for (int kc = 0; kc < 8; ++kc)
                af[mi][kc] = *(const bf16x8_t*)(abase + (size_t)mi * 16 * D + kc * 32);
    }

    float rs[4] = {0.f, 0.f, 0.f, 0.f};

    bf16x8_t b0[2][8], b1[2][8];
    auto loadB = [&](int s, bf16x8_t dst[2][8]) {
        const __bf16* bbase = zb + (size_t)(s * 32 + lane15) * D + quad * 8;
        #pragma unroll
        for (int nj = 0; nj < 2; ++nj)
            #pragma unroll
            for (int kc = 0; kc < 8; ++kc)
                dst[nj][kc] = *(const bf16x8_t*)(bbase + (size_t)nj * 16 * D + kc * 32);
    };
    auto compute = [&](int s, const bf16x8_t bfr[2][8]) {
        f32x4_t acc[4][2] = {};
        #pragma unroll
        for (int kc = 0; kc < 8; ++kc)
            #pragma unroll
            for (int mi = 0; mi < 4; ++mi)
                #pragma unroll
                for (int nj = 0; nj < 2; ++nj)
                    acc[mi][nj] = __builtin_amdgcn_mfma_f32_16x16x32_bf16(
                        bfr[nj][kc], af[mi][kc], acc[mi][nj], 0, 0, 0);
        // acc[mi][nj]: S-row = r0+16*mi+lane15 (lane), S-col = 32*s+16*nj+quad*4+t
        const int  cs     = s * 32;
        const bool masked = (s >= smask);              // wave-uniform
        float cp[2][4] = {};
        #pragma unroll
        for (int mi = 0; mi < 4; ++mi) {
            const int row = r0 + 16 * mi + lane15;
            #pragma unroll
            for (int nj = 0; nj < 2; ++nj)
                #pragma unroll
                for (int t = 0; t < 4; ++t) {
                    const int n = cs + 16 * nj + quad * 4 + t;
                    float e = exp2f(acc[mi][nj][t]);   // = exp(2*sim)
                    if (masked) e = (n < row) ? e : 0.0f;
                    rs[mi]     += e;
                    cp[nj][t]  += e;
                }
        }
        #pragma unroll
        for (int off = 1; off < 16; off <<= 1)
            #pragma unroll
            for (int nj = 0; nj < 2; ++nj)
                #pragma unroll
                for (int t = 0; t < 4; ++t)
                    cp[nj][t] += __shfl_xor(cp[nj][t], off, 64);
        if (lane15 == 0) {
            #pragma unroll
            for (int nj = 0; nj < 2; ++nj)
                #pragma unroll
                for (int t = 0; t < 4; ++t)
                    atomicAdd(&g_denom[cs + 16 * nj + quad * 4 + t], cp[nj][t]);
        }
    };

    loadB(s0, b0);
    int s = s0;
    while (true) {
        if (s + 1 < s1) loadB(s + 1, b1);
        compute(s, b0);
        if (++s >= s1) break;
        if (s + 1 < s1) loadB(s + 1, b0);
        compute(s, b1);
        if (++s >= s1) break;
    }

    // row sums: reduce quad groups once per chunk, 4 atomic instrs
    #pragma unroll
    for (int mi = 0; mi < 4; ++mi) {
        rs[mi] += __shfl_xor(rs[mi], 16, 64);
        rs[mi] += __shfl_xor(rs[mi], 32, 64);
    }
    if (l < 16) {
        #pragma unroll
        for (int mi = 0; mi < 4; ++mi)
            atomicAdd(&g_denom[r0 + 16 * mi + l], rs[mi]);
    }
}

// ---------------- kernel 3: finalize -> scalar loss ----------------
__global__ __launch_bounds__(256) void fin_kernel(const float* __restrict__ g_denom,
                                                  const float* __restrict__ g_pos,
                                                  float* __restrict__ out) {
    const int tid = threadIdx.x;
    float local = 0.0f;
    for (int k = tid; k < N2; k += 256)
        local += logf(g_denom[k]) - 2.0f * g_pos[k];
    #pragma unroll
    for (int off = 32; off; off >>= 1) local += __shfl_xor(local, off, 64);
    __shared__ float sw[4];
    if ((tid & 63) == 0) sw[tid >> 6] = local;
    __syncthreads();
    if (tid == 0) out[0] = (sw[0] + sw[1] + sw[2] + sw[3]) / (float)N2;
}

extern "C" void kernel_launch(void* const* d_in, const int* in_sizes, int n_in,
                              void* d_out, int out_size, void* d_ws, size_t ws_size,
                              hipStream_t stream) {
    const float* emb_i = (const float*)d_in[0];
    const float* emb_j = (const float*)d_in[1];

    __bf16* zb      = (__bf16*)d_ws;                                 // 4 MB
    float*  g_denom = (float*)((char*)d_ws + (size_t)N2 * D * 2);    // 8192 fp32
    float*  g_pos   = g_denom + N2;                                  // 8192 fp32
    float*  out     = (float*)d_out;

    prep_kernel<<<NHALF / 4, 256, 0, stream>>>(emb_i, emb_j, zb, g_pos, g_denom);
    sim_kernel<<<2112, 64, 0, stream>>>(zb, g_denom);   // one wave per block
    fin_kernel<<<1, 256, 0, stream>>>(g_denom, g_pos, out);
}